// Round 6
// baseline (282.580 us; speedup 1.0000x reference)
//
#include <hip/hip_runtime.h>
#include <stdint.h>

#define TT 4096      // tokens
#define DM 1024      // d_model
#define NE 16        // experts
#define DFF 512      // per-expert ffn
#define DFS 1024     // shared ffn
#define CAP 1024     // capacity

typedef unsigned short u16;
typedef __bf16 bf16x8 __attribute__((ext_vector_type(8)));
typedef float f32x4 __attribute__((ext_vector_type(4)));

typedef __attribute__((address_space(1))) void as1_void;
typedef __attribute__((address_space(3))) void as3_void;

__device__ __forceinline__ u16 f2bf(float f) {
  union { float f; uint32_t u; } v; v.f = f;
  uint32_t u = v.u;
  u += 0x7fffu + ((u >> 16) & 1u);   // RNE
  return (u16)(u >> 16);
}

__device__ __forceinline__ float bf2f(u16 b) {
  union { uint32_t u; float f; } v; v.u = ((uint32_t)b) << 16;
  return v.f;
}

__device__ __forceinline__ void gl2lds16(const void* g, void* l) {
  __builtin_amdgcn_global_load_lds(
      (as1_void*)(uintptr_t)g,
      (as3_void*)(uint32_t)(uintptr_t)l,
      16, 0, 0);
}

// ============ PREP: router (+hidden bf16 cast) and all weight transposes ============
// bid < 256: router block (16 tokens; coalesced LDS-staged x, (kchunk,expert) threads)
// bid >= 256: transpose block; tb = bid-256, z = tb>>8, xy = tb&255
//   z decode: [0,16) w1 | [16,32) w3 | [32,48) w2 | 48 ws1 | 49 ws3 | 50 ws2
__global__ __launch_bounds__(256) void k_prep(
    const float* __restrict__ x, const float* __restrict__ Wg,
    const float* __restrict__ w1, const float* __restrict__ w3,
    const float* __restrict__ w2, const float* __restrict__ ws1,
    const float* __restrict__ ws3, const float* __restrict__ ws2,
    u16* __restrict__ hbf,
    u16* __restrict__ w1t, u16* __restrict__ w3t, u16* __restrict__ w2t,
    u16* __restrict__ ws1t, u16* __restrict__ ws3t, u16* __restrict__ ws2t,
    int* __restrict__ counts, int* __restrict__ tok_slot,
    int* __restrict__ tslot, float* __restrict__ tw) {
  __shared__ __align__(16) char smraw[18496];
  __shared__ int pick_e[32];     // per-block (token,k) expert picks
  __shared__ int base_sh[16];    // per-block expert base slot from one atomic each
  const int bid = blockIdx.x;
  const int tid = threadIdx.x;

  if (bid < 256) {
    // ---------------- router (coalesced) ----------------
    float* x_lds = (float*)smraw;
    float (*lg)[17] = (float(*)[17])(smraw + 17408);          // [token][expert]
    const int e16 = tid & 15;
    const int kpc = tid >> 4;
    const int t0 = bid * 16;
    const int col = (tid & 63) * 4;    // staging column
    const int rsub = tid >> 6;         // staging row-sub (wave id)

    float acc[16];
#pragma unroll
    for (int t = 0; t < 16; ++t) acc[t] = 0.f;

    for (int q = 0; q < 4; ++q) {
      if (q) __syncthreads();          // protect x_lds before overwrite
#pragma unroll
      for (int p = 0; p < 4; ++p) {
        int r = p * 4 + rsub;
        float4 xv = *(const float4*)&x[(size_t)(t0 + r) * DM + q * 256 + col];
        ushort4 o;
        o.x = f2bf(xv.x); o.y = f2bf(xv.y); o.z = f2bf(xv.z); o.w = f2bf(xv.w);
        *(ushort4*)&hbf[(size_t)(t0 + r) * DM + q * 256 + col] = o;
        *(float4*)&x_lds[r * 256 + col] = xv;
      }
      __syncthreads();
      float wg[16];
#pragma unroll
      for (int i = 0; i < 16; ++i)
        wg[i] = Wg[(size_t)(q * 256 + kpc * 16 + i) * NE + e16];
#pragma unroll
      for (int t = 0; t < 16; ++t) {
        const float4* xp = (const float4*)&x_lds[t * 256 + kpc * 16];
        float4 a0 = xp[0], a1 = xp[1], a2 = xp[2], a3 = xp[3];
        float s = acc[t];
        s += a0.x * wg[0]  + a0.y * wg[1]  + a0.z * wg[2]  + a0.w * wg[3];
        s += a1.x * wg[4]  + a1.y * wg[5]  + a1.z * wg[6]  + a1.w * wg[7];
        s += a2.x * wg[8]  + a2.y * wg[9]  + a2.z * wg[10] + a2.w * wg[11];
        s += a3.x * wg[12] + a3.y * wg[13] + a3.z * wg[14] + a3.w * wg[15];
        acc[t] = s;
      }
    }
    __syncthreads();
    float* red = (float*)smraw;
#pragma unroll
    for (int t = 0; t < 16; ++t) red[kpc * 272 + t * 16 + e16] = acc[t];
    __syncthreads();
    {
      int t2 = tid >> 4, e2 = tid & 15;
      float s = 0.f;
#pragma unroll
      for (int k2 = 0; k2 < 16; ++k2) s += red[k2 * 272 + t2 * 16 + e2];
      lg[t2][e2] = s;
    }
    __syncthreads();
    if (e16 == 0) {
      int tl = kpc;
      int t = t0 + tl;
      float b0 = -1e30f; int i0 = 0;
#pragma unroll
      for (int i = 0; i < NE; ++i) { float v = lg[tl][i]; if (v > b0) { b0 = v; i0 = i; } }
      float b1 = -1e30f; int i1 = 0;
#pragma unroll
      for (int i = 0; i < NE; ++i) { if (i == i0) continue; float v = lg[tl][i]; if (v > b1) { b1 = v; i1 = i; } }
      float ex = __expf(b1 - b0);
      float w0 = 1.f / (1.f + ex);
      float w1v = 1.f - w0;
      pick_e[2 * tl] = i0;
      pick_e[2 * tl + 1] = i1;
      tw[2 * t] = w0; tw[2 * t + 1] = w1v;
    }
    __syncthreads();
    if (tid < 16) {
      int c = 0;
#pragma unroll
      for (int j = 0; j < 32; ++j) c += (pick_e[j] == tid) ? 1 : 0;
      int base = 0;
      if (c > 0) base = atomicAdd(&counts[tid], c);
      base_sh[tid] = base;
    }
    __syncthreads();
    if (e16 == 0) {
      int tl = kpc;
      int t = t0 + tl;
#pragma unroll
      for (int kk = 0; kk < 2; ++kk) {
        int idx = 2 * tl + kk;
        int e = pick_e[idx];
        int rank = 0;
        for (int j = 0; j < idx; ++j) rank += (pick_e[j] == e) ? 1 : 0;
        int p = base_sh[e] + rank;
        int s = -1;
        if (p < CAP) { s = e * CAP + p; tok_slot[s] = t; }
        tslot[2 * t + kk] = s;
      }
    }
    return;
  }

  // ---------------- transpose-convert fp32 [R,C] -> bf16 [C,R] ----------------
  int tb = bid - 256;
  int z = tb >> 8, xy = tb & 255;
  const float* ip; u16* op; int R, C;
  if (z < 16)      { ip = w1 + (size_t)z * DM * DFF;       op = w1t + (size_t)z * DM * DFF;       R = DM;  C = DFF; }
  else if (z < 32) { int e = z - 16; ip = w3 + (size_t)e * DM * DFF; op = w3t + (size_t)e * DM * DFF; R = DM;  C = DFF; }
  else if (z < 48) { int e = z - 32; ip = w2 + (size_t)e * DFF * DM; op = w2t + (size_t)e * DFF * DM; R = DFF; C = DM; }
  else if (z == 48){ ip = ws1; op = ws1t; R = DM;  C = DFS; }
  else if (z == 49){ ip = ws3; op = ws3t; R = DM;  C = DFS; }
  else             { ip = ws2; op = ws2t; R = DFS; C = DM; }

  int c0 = (xy & 15) * 64, r0 = (xy >> 4) * 64;
  if (c0 >= C || r0 >= R) return;   // block-uniform

  // pad 65: read bank = (4*tx + ty) % 32 -> all 32 banks, 2-way only
  float (*tile)[65] = (float(*)[65])smraw;   // 64 x 65 fp32 = 16640 B
  int tx = tid & 15, ty = tid >> 4;
#pragma unroll
  for (int j = 0; j < 4; ++j) {
    int r = ty + 16 * j;
    float4 v = *(const float4*)&ip[(size_t)(r0 + r) * C + c0 + tx * 4];
    *(float4*)&tile[r][tx * 4] = v;
  }
  __syncthreads();
#pragma unroll
  for (int j = 0; j < 4; ++j) {
    int c = ty + 16 * j;
    ushort4 o;
    o.x = f2bf(tile[tx * 4 + 0][c]);
    o.y = f2bf(tile[tx * 4 + 1][c]);
    o.z = f2bf(tile[tx * 4 + 2][c]);
    o.w = f2bf(tile[tx * 4 + 3][c]);
    *(ushort4*)&op[(size_t)(c0 + c) * R + r0 + tx * 4] = o;
  }
}

// LDS tile rows are 64 u16 = 128B = 8 chunks of 16B; chunk c of row r in slot c^(r&7).
#define FRAG(BUF, ROW, CC)                                                       \
  (*(const bf16x8*)&BUF[(ROW) * 64 + ((((CC) * 4 + lq) ^ ((ROW) & 7)) << 3)])

// ============ UP: 128x64 tile, 4 waves, BK=64, dual-B, dbuf + COUNTED VMCNT ============
// swz < 512: shared (A=hbf, B=ws1t/ws3t, C=hs, N=DFS)
// swz >= 512: routed (A=gather(hbf), B=w1t/w3t[e], C=hexp[e], N=DFF)
__global__ __launch_bounds__(256) void k_up(
    const u16* __restrict__ hbf,
    const u16* __restrict__ ws1t, const u16* __restrict__ ws3t,
    const u16* __restrict__ w1t, const u16* __restrict__ w3t,
    u16* __restrict__ hs, u16* __restrict__ hexp,
    const int* __restrict__ counts, const int* __restrict__ tok_slot) {
  const int tid = threadIdx.x;
  // XCD-aware bijective swizzle: nwg=1536 (divisible by 8).
  const int nwg = 512 + NE * 64;
  int bid = (int)blockIdx.x;
  bid = (bid & 7) * (nwg >> 3) + (bid >> 3);

  const u16* B1p; const u16* B3p; u16* Cp;
  int m0, n0, N;
  int e = -1, cnt = 0;
  if (bid < 512) {
    m0 = (bid >> 4) * 128; n0 = (bid & 15) * 64;
    B1p = ws1t; B3p = ws3t; Cp = hs; N = DFS;
  } else {
    int r = bid - 512;                  // 1024 routed: e * (8 m-tiles x 8 n-tiles)
    e = r >> 6; int q = r & 63;
    m0 = (q >> 3) * 128; n0 = (q & 7) * 64;
    cnt = counts[e]; if (cnt > CAP) cnt = CAP;
    if (m0 >= cnt) return;              // uniform exit before any barrier
    B1p = w1t + (size_t)e * (DFF * DM);
    B3p = w3t + (size_t)e * (DFF * DM);
    Cp = hexp + (size_t)e * (CAP * DFF);
    N = DFF;
  }

  __shared__ __align__(16) u16 As[2][128 * 64];   // 32 KB
  __shared__ __align__(16) u16 Bs1[2][64 * 64];   // 16 KB
  __shared__ __align__(16) u16 Bs3[2][64 * 64];   // 16 KB

  uint32_t aoff[4], boff[2];
#pragma unroll
  for (int j = 0; j < 4; ++j) {
    int L = tid + 256 * j;
    int row = L >> 3;
    int c = (L & 7) ^ (row & 7);
    int gr;
    if (e >= 0) {
      int rr = m0 + row;
      gr = (rr < cnt) ? tok_slot[e * CAP + rr] : 0;
    } else {
      gr = m0 + row;
    }
    aoff[j] = (uint32_t)gr * DM + c * 8;
  }
#pragma unroll
  for (int j = 0; j < 2; ++j) {
    int L = tid + 256 * j;
    int row = L >> 3;
    int c = (L & 7) ^ (row & 7);
    boff[j] = (uint32_t)(n0 + row) * DM + c * 8;
  }

  const int lane = tid & 63;
  const int wv = tid >> 6;
  const int wr = wv * 32;       // 4 waves x 32 rows
  const int lr = lane & 15;
  const int lq = lane >> 4;

  f32x4 acc1[2][4], acc3[2][4];
#pragma unroll
  for (int i = 0; i < 2; ++i)
#pragma unroll
    for (int j = 0; j < 4; ++j) {
      acc1[i][j] = (f32x4){0.f, 0.f, 0.f, 0.f};
      acc3[i][j] = (f32x4){0.f, 0.f, 0.f, 0.f};
    }

#define UP_STAGE(B, K0)                                                              \
  do {                                                                               \
    _Pragma("unroll")                                                                \
    for (int j = 0; j < 4; ++j)                                                      \
      gl2lds16(hbf + aoff[j] + (K0), &As[B][(size_t)(tid + 256 * j) * 8]);           \
    _Pragma("unroll")                                                                \
    for (int j = 0; j < 2; ++j)                                                      \
      gl2lds16(B1p + boff[j] + (K0), &Bs1[B][(size_t)(tid + 256 * j) * 8]);          \
    _Pragma("unroll")                                                                \
    for (int j = 0; j < 2; ++j)                                                      \
      gl2lds16(B3p + boff[j] + (K0), &Bs3[B][(size_t)(tid + 256 * j) * 8]);          \
  } while (0)

#define UP_COMPUTE(B)                                                                \
  do {                                                                               \
    const u16* Ab = &As[B][0];                                                       \
    const u16* B1b = &Bs1[B][0];                                                     \
    const u16* B3b = &Bs3[B][0];                                                     \
    _Pragma("unroll")                                                                \
    for (int cc = 0; cc < 2; ++cc) {                                                 \
      bf16x8 af[2], bf1[4], bf3[4];                                                  \
      _Pragma("unroll")                                                              \
      for (int i = 0; i < 2; ++i) af[i] = FRAG(Ab, wr + i * 16 + lr, cc);            \
      _Pragma("unroll")                                                              \
      for (int j = 0; j < 4; ++j) {                                                  \
        bf1[j] = FRAG(B1b, j * 16 + lr, cc);                                         \
        bf3[j] = FRAG(B3b, j * 16 + lr, cc);                                         \
      }                                                                              \
      _Pragma("unroll")                                                              \
      for (int i = 0; i < 2; ++i)                                                    \
        _Pragma("unroll")                                                            \
        for (int j = 0; j < 4; ++j) {                                                \
          acc1[i][j] = __builtin_amdgcn_mfma_f32_16x16x32_bf16(af[i], bf1[j], acc1[i][j], 0, 0, 0); \
          acc3[i][j] = __builtin_amdgcn_mfma_f32_16x16x32_bf16(af[i], bf3[j], acc3[i][j], 0, 0, 0); \
        }                                                                            \
    }                                                                                \
  } while (0)

  // counted-vmcnt 2-phase: fresh stage's 8 loads stay in flight across the barrier.
  // vmcnt(8) = wait only for the PREVIOUS stage (current buffer) to land.
  UP_STAGE(0, 0);
  int cur = 0;
  const int NT = DM / 64;
#pragma unroll 1
  for (int t = 0; t < NT - 1; ++t) {
    UP_STAGE(cur ^ 1, (t + 1) * 64);
    asm volatile("s_waitcnt vmcnt(8)" ::: "memory");
    __builtin_amdgcn_s_barrier();           // cur buffer ready for all waves
    UP_COMPUTE(cur);
    __builtin_amdgcn_s_barrier();           // all waves done reading cur before overwrite
    cur ^= 1;
  }
  asm volatile("s_waitcnt vmcnt(0)" ::: "memory");
  __builtin_amdgcn_s_barrier();
  UP_COMPUTE(cur);

#pragma unroll
  for (int i = 0; i < 2; ++i)
#pragma unroll
    for (int r = 0; r < 4; ++r) {
      int row = m0 + wr + i * 16 + lq * 4 + r;
      u16* crow = Cp + (size_t)row * N;
#pragma unroll
      for (int j = 0; j < 4; ++j) {
        float v1 = acc1[i][j][r];
        float v3 = acc3[i][j][r];
        float h = (v1 / (1.f + __expf(-v1))) * v3;   // silu(v1)*v3
        crow[n0 + j * 16 + lr] = f2bf(h);
      }
    }
}

// ============ DOWN: 128x64 tile, 4 waves, BK=64, single-B, dbuf + COUNTED VMCNT ========
// swz < 512: shared (A=hs, B=ws2t, K=DFS) -> out fp32 (covers every element)
// swz >= 512: routed (A=hexp[e], B=w2t[e], K=DFF) -> ob bf16 per-slot rows
__global__ __launch_bounds__(256) void k_down(
    const u16* __restrict__ hs, const u16* __restrict__ ws2t,
    const u16* __restrict__ hexp, const u16* __restrict__ w2t,
    float* __restrict__ out, u16* __restrict__ ob,
    const int* __restrict__ counts) {
  const int tid = threadIdx.x;
  const int nwg = 512 + NE * 128;   // 2560, divisible by 8
  int bid = (int)blockIdx.x;
  bid = (bid & 7) * (nwg >> 3) + (bid >> 3);

  const u16* Ap; const u16* Bp;
  int m0, n0, K, e = -1;
  if (bid < 512) {
    m0 = (bid >> 4) * 128; n0 = (bid & 15) * 64;
    Ap = hs; Bp = ws2t; K = DFS;
  } else {
    int r = bid - 512;                  // 2048 routed: e * (8 m-tiles x 16 n-tiles)
    e = r >> 7; int q = r & 127;
    m0 = (q >> 4) * 128; n0 = (q & 15) * 64;
    int cnt = counts[e]; if (cnt > CAP) cnt = CAP;
    if (m0 >= cnt) return;
    Ap = hexp + (size_t)e * (CAP * DFF);
    Bp = w2t + (size_t)e * (DM * DFF);
    K = DFF;
  }

  __shared__ __align__(16) u16 As[2][128 * 64];   // 32 KB
  __shared__ __align__(16) u16 Bs[2][64 * 64];    // 16 KB

  uint32_t aoff[4], boff[2];
#pragma unroll
  for (int j = 0; j < 4; ++j) {
    int L = tid + 256 * j;
    int row = L >> 3;
    int c = (L & 7) ^ (row & 7);
    aoff[j] = (uint32_t)(m0 + row) * K + c * 8;
  }
#pragma unroll
  for (int j = 0; j < 2; ++j) {
    int L = tid + 256 * j;
    int row = L >> 3;
    int c = (L & 7) ^ (row & 7);
    boff[j] = (uint32_t)(n0 + row) * K + c * 8;
  }

  const int lane = tid & 63;
  const int wv = tid >> 6;
  const int wr = wv * 32;
  const int lr = lane & 15;
  const int lq = lane >> 4;

  f32x4 acc[2][4];
#pragma unroll
  for (int i = 0; i < 2; ++i)
#pragma unroll
    for (int j = 0; j < 4; ++j) acc[i][j] = (f32x4){0.f, 0.f, 0.f, 0.f};

#define DN_STAGE(B, K0)                                                              \
  do {                                                                               \
    _Pragma("unroll")                                                                \
    for (int j = 0; j < 4; ++j)                                                      \
      gl2lds16(Ap + aoff[j] + (K0), &As[B][(size_t)(tid + 256 * j) * 8]);            \
    _Pragma("unroll")                                                                \
    for (int j = 0; j < 2; ++j)                                                      \
      gl2lds16(Bp + boff[j] + (K0), &Bs[B][(size_t)(tid + 256 * j) * 8]);            \
  } while (0)

#define DN_COMPUTE(B)                                                                \
  do {                                                                               \
    const u16* Ab = &As[B][0];                                                       \
    const u16* Bb = &Bs[B][0];                                                       \
    _Pragma("unroll")                                                                \
    for (int cc = 0; cc < 2; ++cc) {                                                 \
      bf16x8 af[2], bfr[4];                                                          \
      _Pragma("unroll")                                                              \
      for (int i = 0; i < 2; ++i) af[i] = FRAG(Ab, wr + i * 16 + lr, cc);            \
      _Pragma("unroll")                                                              \
      for (int j = 0; j < 4; ++j) bfr[j] = FRAG(Bb, j * 16 + lr, cc);                \
      _Pragma("unroll")                                                              \
      for (int i = 0; i < 2; ++i)                                                    \
        _Pragma("unroll")                                                            \
        for (int j = 0; j < 4; ++j)                                                  \
          acc[i][j] = __builtin_amdgcn_mfma_f32_16x16x32_bf16(af[i], bfr[j], acc[i][j], 0, 0, 0); \
    }                                                                                \
  } while (0)

  DN_STAGE(0, 0);
  int cur = 0;
  const int NT = K / 64;
#pragma unroll 1
  for (int t = 0; t < NT - 1; ++t) {
    DN_STAGE(cur ^ 1, (t + 1) * 64);
    asm volatile("s_waitcnt vmcnt(6)" ::: "memory");
    __builtin_amdgcn_s_barrier();
    DN_COMPUTE(cur);
    __builtin_amdgcn_s_barrier();
    cur ^= 1;
  }
  asm volatile("s_waitcnt vmcnt(0)" ::: "memory");
  __builtin_amdgcn_s_barrier();
  DN_COMPUTE(cur);

  if (e < 0) {
#pragma unroll
    for (int i = 0; i < 2; ++i)
#pragma unroll
      for (int r = 0; r < 4; ++r) {
        int row = m0 + wr + i * 16 + lq * 4 + r;
        float* orow = out + (size_t)row * DM;
#pragma unroll
        for (int j = 0; j < 4; ++j)
          orow[n0 + j * 16 + lr] = acc[i][j][r];
      }
  } else {
    u16* obase = ob + (size_t)e * CAP * DM;
#pragma unroll
    for (int i = 0; i < 2; ++i)
#pragma unroll
      for (int r = 0; r < 4; ++r) {
        int row = m0 + wr + i * 16 + lq * 4 + r;
        u16* orow = obase + (size_t)row * DM;
#pragma unroll
        for (int j = 0; j < 4; ++j)
          orow[n0 + j * 16 + lr] = f2bf(acc[i][j][r]);
      }
  }
}

// ============ COMBINE: out[t] += w0*ob[s0] + w1*ob[s1] ============
__global__ __launch_bounds__(256) void k_combine(
    float* __restrict__ out, const u16* __restrict__ ob,
    const int* __restrict__ tslot, const float* __restrict__ tw) {
  int t = blockIdx.x;
  int c = threadIdx.x * 4;
  int s0 = tslot[2 * t], s1 = tslot[2 * t + 1];
  float w0 = tw[2 * t], w1 = tw[2 * t + 1];
  float4 v = *(float4*)&out[(size_t)t * DM + c];
  if (s0 >= 0) {
    ushort4 o = *(const ushort4*)&ob[(size_t)s0 * DM + c];
    v.x += w0 * bf2f(o.x); v.y += w0 * bf2f(o.y);
    v.z += w0 * bf2f(o.z); v.w += w0 * bf2f(o.w);
  }
  if (s1 >= 0) {
    ushort4 o = *(const ushort4*)&ob[(size_t)s1 * DM + c];
    v.x += w1 * bf2f(o.x); v.y += w1 * bf2f(o.y);
    v.z += w1 * bf2f(o.z); v.w += w1 * bf2f(o.w);
  }
  *(float4*)&out[(size_t)t * DM + c] = v;
}

// ---------------- host ----------------
extern "C" void kernel_launch(void* const* d_in, const int* in_sizes, int n_in,
                              void* d_out, int out_size, void* d_ws, size_t ws_size,
                              hipStream_t stream) {
  (void)in_sizes; (void)n_in; (void)out_size; (void)ws_size;
  const float* x   = (const float*)d_in[0];
  const float* Wg  = (const float*)d_in[1];
  const float* w1  = (const float*)d_in[2];
  const float* w3  = (const float*)d_in[3];
  const float* w2  = (const float*)d_in[4];
  const float* ws1 = (const float*)d_in[5];
  const float* ws3 = (const float*)d_in[6];
  const float* ws2 = (const float*)d_in[7];
  float* out = (float*)d_out;
  char* ws = (char*)d_ws;

  u16* hbf   = (u16*)(ws + 0);          // 8 MB   [TT,DM] bf16          (dead after k_up)
  u16* w1t   = (u16*)(ws + 8388608);    // 16 MB  [E][DFF][DM]          (dead after k_up)
  u16* w3t   = (u16*)(ws + 25165824);   // 16 MB                        (dead after k_up)
  u16* w2t   = (u16*)(ws + 41943040);   // 16 MB  [E][DM][DFF]
  u16* ws1t  = (u16*)(ws + 58720256);   // 2 MB   [DFS][DM]
  u16* ws3t  = (u16*)(ws + 60817408);   // 2 MB
  u16* ws2t  = (u16*)(ws + 62914560);   // 2 MB   [DM][DFS]
  u16* hs    = (u16*)(ws + 65011712);   // 8 MB   [TT,DFS] bf16
  u16* hexp  = (u16*)(ws + 73400320);   // 16 MB  [E][CAP][DFF] bf16
  int* counts    = (int*)(ws + 90177536);
  int* tok_slot  = (int*)(ws + 90177792);   // 64 KB
  int* tslot     = (int*)(ws + 90243328);   // 32 KB [TT*2]
  float* tw      = (float*)(ws + 90276096); // 32 KB [TT*2]
  u16* ob    = (u16*)(ws + 0);          // 33.5 MB [E*CAP, DM] bf16 — aliases hbf/w1t/w3t
                                        // (written only in k_down, after those are dead)

  hipMemsetAsync(counts, 0, NE * sizeof(int), stream);

  // prep: 256 router blocks + 51*256 transpose blocks
  k_prep<<<dim3(256 + 51 * 256), dim3(256), 0, stream>>>(
      x, Wg, w1, w3, w2, ws1, ws3, ws2,
      hbf, w1t, w3t, w2t, ws1t, ws3t, ws2t,
      counts, tok_slot, tslot, tw);

  // up: 512 shared tiles (32m x 16n) + 1024 routed tiles (16e x 8m x 8n)
  k_up<<<dim3(512 + NE * 64), dim3(256), 0, stream>>>(
      hbf, ws1t, ws3t, w1t, w3t, hs, hexp, counts, tok_slot);

  // down: 512 shared tiles -> out (plain fp32) + 2048 routed tiles -> ob (plain bf16)
  k_down<<<dim3(512 + NE * 128), dim3(256), 0, stream>>>(
      hs, ws2t, hexp, w2t, out, ob, counts);

  // combine: out[t] += w0*ob[s0] + w1*ob[s1]
  k_combine<<<dim3(TT), dim3(256), 0, stream>>>(out, ob, tslot, tw);
}

// Round 7
// 279.546 us; speedup vs baseline: 1.0109x; 1.0109x over previous
//
#include <hip/hip_runtime.h>
#include <stdint.h>

#define TT 4096      // tokens
#define DM 1024      // d_model
#define NE 16        // experts
#define DFF 512      // per-expert ffn
#define DFS 1024     // shared ffn
#define CAP 1024     // capacity

typedef unsigned short u16;
typedef __bf16 bf16x8 __attribute__((ext_vector_type(8)));
typedef float f32x4 __attribute__((ext_vector_type(4)));

typedef __attribute__((address_space(1))) void as1_void;
typedef __attribute__((address_space(3))) void as3_void;

__device__ __forceinline__ u16 f2bf(float f) {
  union { float f; uint32_t u; } v; v.f = f;
  uint32_t u = v.u;
  u += 0x7fffu + ((u >> 16) & 1u);   // RNE
  return (u16)(u >> 16);
}

__device__ __forceinline__ float bf2f(u16 b) {
  union { uint32_t u; float f; } v; v.u = ((uint32_t)b) << 16;
  return v.f;
}

__device__ __forceinline__ void gl2lds16(const void* g, void* l) {
  __builtin_amdgcn_global_load_lds(
      (as1_void*)(uintptr_t)g,
      (as3_void*)(uint32_t)(uintptr_t)l,
      16, 0, 0);
}

// ============ PREP: router (+hidden bf16 cast) and all weight transposes ============
// bid < 256: router block (16 tokens; coalesced LDS-staged x, (kchunk,expert) threads)
// bid >= 256: transpose block; tb = bid-256, z = tb>>8, xy = tb&255
//   z decode: [0,16) w1 | [16,32) w3 | [32,48) w2 | 48 ws1 | 49 ws3 | 50 ws2
__global__ __launch_bounds__(256) void k_prep(
    const float* __restrict__ x, const float* __restrict__ Wg,
    const float* __restrict__ w1, const float* __restrict__ w3,
    const float* __restrict__ w2, const float* __restrict__ ws1,
    const float* __restrict__ ws3, const float* __restrict__ ws2,
    u16* __restrict__ hbf,
    u16* __restrict__ w1t, u16* __restrict__ w3t, u16* __restrict__ w2t,
    u16* __restrict__ ws1t, u16* __restrict__ ws3t, u16* __restrict__ ws2t,
    int* __restrict__ counts, int* __restrict__ tok_slot,
    int* __restrict__ tslot, float* __restrict__ tw) {
  __shared__ __align__(16) char smraw[18496];
  __shared__ int pick_e[32];     // per-block (token,k) expert picks
  __shared__ int base_sh[16];    // per-block expert base slot from one atomic each
  const int bid = blockIdx.x;
  const int tid = threadIdx.x;

  if (bid < 256) {
    // ---------------- router (coalesced) ----------------
    float* x_lds = (float*)smraw;
    float (*lg)[17] = (float(*)[17])(smraw + 17408);          // [token][expert]
    const int e16 = tid & 15;
    const int kpc = tid >> 4;
    const int t0 = bid * 16;
    const int col = (tid & 63) * 4;    // staging column
    const int rsub = tid >> 6;         // staging row-sub (wave id)

    float acc[16];
#pragma unroll
    for (int t = 0; t < 16; ++t) acc[t] = 0.f;

    for (int q = 0; q < 4; ++q) {
      if (q) __syncthreads();          // protect x_lds before overwrite
#pragma unroll
      for (int p = 0; p < 4; ++p) {
        int r = p * 4 + rsub;
        float4 xv = *(const float4*)&x[(size_t)(t0 + r) * DM + q * 256 + col];
        ushort4 o;
        o.x = f2bf(xv.x); o.y = f2bf(xv.y); o.z = f2bf(xv.z); o.w = f2bf(xv.w);
        *(ushort4*)&hbf[(size_t)(t0 + r) * DM + q * 256 + col] = o;
        *(float4*)&x_lds[r * 256 + col] = xv;
      }
      __syncthreads();
      float wg[16];
#pragma unroll
      for (int i = 0; i < 16; ++i)
        wg[i] = Wg[(size_t)(q * 256 + kpc * 16 + i) * NE + e16];
#pragma unroll
      for (int t = 0; t < 16; ++t) {
        const float4* xp = (const float4*)&x_lds[t * 256 + kpc * 16];
        float4 a0 = xp[0], a1 = xp[1], a2 = xp[2], a3 = xp[3];
        float s = acc[t];
        s += a0.x * wg[0]  + a0.y * wg[1]  + a0.z * wg[2]  + a0.w * wg[3];
        s += a1.x * wg[4]  + a1.y * wg[5]  + a1.z * wg[6]  + a1.w * wg[7];
        s += a2.x * wg[8]  + a2.y * wg[9]  + a2.z * wg[10] + a2.w * wg[11];
        s += a3.x * wg[12] + a3.y * wg[13] + a3.z * wg[14] + a3.w * wg[15];
        acc[t] = s;
      }
    }
    __syncthreads();
    float* red = (float*)smraw;
#pragma unroll
    for (int t = 0; t < 16; ++t) red[kpc * 272 + t * 16 + e16] = acc[t];
    __syncthreads();
    {
      int t2 = tid >> 4, e2 = tid & 15;
      float s = 0.f;
#pragma unroll
      for (int k2 = 0; k2 < 16; ++k2) s += red[k2 * 272 + t2 * 16 + e2];
      lg[t2][e2] = s;
    }
    __syncthreads();
    if (e16 == 0) {
      int tl = kpc;
      int t = t0 + tl;
      float b0 = -1e30f; int i0 = 0;
#pragma unroll
      for (int i = 0; i < NE; ++i) { float v = lg[tl][i]; if (v > b0) { b0 = v; i0 = i; } }
      float b1 = -1e30f; int i1 = 0;
#pragma unroll
      for (int i = 0; i < NE; ++i) { if (i == i0) continue; float v = lg[tl][i]; if (v > b1) { b1 = v; i1 = i; } }
      float ex = __expf(b1 - b0);
      float w0 = 1.f / (1.f + ex);
      float w1v = 1.f - w0;
      pick_e[2 * tl] = i0;
      pick_e[2 * tl + 1] = i1;
      tw[2 * t] = w0; tw[2 * t + 1] = w1v;
    }
    __syncthreads();
    if (tid < 16) {
      int c = 0;
#pragma unroll
      for (int j = 0; j < 32; ++j) c += (pick_e[j] == tid) ? 1 : 0;
      int base = 0;
      if (c > 0) base = atomicAdd(&counts[tid], c);
      base_sh[tid] = base;
    }
    __syncthreads();
    if (e16 == 0) {
      int tl = kpc;
      int t = t0 + tl;
#pragma unroll
      for (int kk = 0; kk < 2; ++kk) {
        int idx = 2 * tl + kk;
        int e = pick_e[idx];
        int rank = 0;
        for (int j = 0; j < idx; ++j) rank += (pick_e[j] == e) ? 1 : 0;
        int p = base_sh[e] + rank;
        int s = -1;
        if (p < CAP) { s = e * CAP + p; tok_slot[s] = t; }
        tslot[2 * t + kk] = s;
      }
    }
    return;
  }

  // ---------------- transpose-convert fp32 [R,C] -> bf16 [C,R] ----------------
  int tb = bid - 256;
  int z = tb >> 8, xy = tb & 255;
  const float* ip; u16* op; int R, C;
  if (z < 16)      { ip = w1 + (size_t)z * DM * DFF;       op = w1t + (size_t)z * DM * DFF;       R = DM;  C = DFF; }
  else if (z < 32) { int e = z - 16; ip = w3 + (size_t)e * DM * DFF; op = w3t + (size_t)e * DM * DFF; R = DM;  C = DFF; }
  else if (z < 48) { int e = z - 32; ip = w2 + (size_t)e * DFF * DM; op = w2t + (size_t)e * DFF * DM; R = DFF; C = DM; }
  else if (z == 48){ ip = ws1; op = ws1t; R = DM;  C = DFS; }
  else if (z == 49){ ip = ws3; op = ws3t; R = DM;  C = DFS; }
  else             { ip = ws2; op = ws2t; R = DFS; C = DM; }

  int c0 = (xy & 15) * 64, r0 = (xy >> 4) * 64;
  if (c0 >= C || r0 >= R) return;   // block-uniform

  // pad 65: read bank = (4*tx + ty) % 32 -> all 32 banks, 2-way only
  float (*tile)[65] = (float(*)[65])smraw;   // 64 x 65 fp32 = 16640 B
  int tx = tid & 15, ty = tid >> 4;
#pragma unroll
  for (int j = 0; j < 4; ++j) {
    int r = ty + 16 * j;
    float4 v = *(const float4*)&ip[(size_t)(r0 + r) * C + c0 + tx * 4];
    *(float4*)&tile[r][tx * 4] = v;
  }
  __syncthreads();
#pragma unroll
  for (int j = 0; j < 4; ++j) {
    int c = ty + 16 * j;
    ushort4 o;
    o.x = f2bf(tile[tx * 4 + 0][c]);
    o.y = f2bf(tile[tx * 4 + 1][c]);
    o.z = f2bf(tile[tx * 4 + 2][c]);
    o.w = f2bf(tile[tx * 4 + 3][c]);
    *(ushort4*)&op[(size_t)(c0 + c) * R + r0 + tx * 4] = o;
  }
}

// BK=32 LDS tiles: row = 32 u16 = 64B = 4 chunks of 16B.
// Staged: LDS slot s of row r holds global chunk s^((r>>1)&3).
// Read: global chunk lq lives at slot lq^((r>>1)&3) -> 2-way bank aliasing (free).
#define FRAG32(BUF, ROW)                                                         \
  (*(const bf16x8*)&BUF[(ROW) * 32 + (((lq) ^ (((ROW) >> 1) & 3)) << 3)])

// ============ UP: 128x128 tile, 4 waves (64x64 each), BK=32, dual-B, dbuf ============
// swz < 256: shared (A=hbf, B=ws1t/ws3t, C=hs, N=DFS)
// swz >= 256: routed (A=gather(hbf), B=w1t/w3t[e], C=hexp[e], N=DFF)
__global__ __launch_bounds__(256, 3) void k_up(
    const u16* __restrict__ hbf,
    const u16* __restrict__ ws1t, const u16* __restrict__ ws3t,
    const u16* __restrict__ w1t, const u16* __restrict__ w3t,
    u16* __restrict__ hs, u16* __restrict__ hexp,
    const int* __restrict__ counts, const int* __restrict__ tok_slot) {
  const int tid = threadIdx.x;
  // XCD-aware bijective swizzle: nwg=768 (divisible by 8)
  const int nwg = 256 + NE * 32;
  int bid = (int)blockIdx.x;
  bid = (bid & 7) * (nwg >> 3) + (bid >> 3);

  const u16* B1p; const u16* B3p; u16* Cp;
  int m0, n0, N;
  int e = -1, cnt = 0;
  if (bid < 256) {
    m0 = (bid >> 3) * 128; n0 = (bid & 7) * 128;
    B1p = ws1t; B3p = ws3t; Cp = hs; N = DFS;
  } else {
    int r = bid - 256;                  // 512 routed: e * (8 m-tiles x 4 n-tiles)
    e = r >> 5; int q = r & 31;
    m0 = (q >> 2) * 128; n0 = (q & 3) * 128;
    cnt = counts[e]; if (cnt > CAP) cnt = CAP;
    if (m0 >= cnt) return;              // uniform exit before any barrier
    B1p = w1t + (size_t)e * (DFF * DM);
    B3p = w3t + (size_t)e * (DFF * DM);
    Cp = hexp + (size_t)e * (CAP * DFF);
    N = DFF;
  }

  __shared__ __align__(16) u16 As[2][128 * 32];   // 16 KB
  __shared__ __align__(16) u16 Bs1[2][128 * 32];  // 16 KB
  __shared__ __align__(16) u16 Bs3[2][128 * 32];  // 16 KB  -> 48 KB total

  uint32_t aoff[2], boff[2];
#pragma unroll
  for (int j = 0; j < 2; ++j) {
    int L = tid + 256 * j;          // [0,512): 128 rows x 4 chunks
    int row = L >> 2;
    int c = (L & 3) ^ ((row >> 1) & 3);
    int gr;
    if (e >= 0) {
      int rr = m0 + row;
      gr = (rr < cnt) ? tok_slot[e * CAP + rr] : 0;
    } else {
      gr = m0 + row;
    }
    aoff[j] = (uint32_t)gr * DM + c * 8;
  }
#pragma unroll
  for (int j = 0; j < 2; ++j) {
    int L = tid + 256 * j;
    int row = L >> 2;
    int c = (L & 3) ^ ((row >> 1) & 3);
    boff[j] = (uint32_t)(n0 + row) * DM + c * 8;
  }

  const int lane = tid & 63;
  const int wv = tid >> 6;
  const int wr = (wv >> 1) * 64;    // 2x2 wave grid, 64x64 per wave
  const int wc = (wv & 1) * 64;
  const int lr = lane & 15;
  const int lq = lane >> 4;

  f32x4 acc1[4][4], acc3[4][4];
#pragma unroll
  for (int i = 0; i < 4; ++i)
#pragma unroll
    for (int j = 0; j < 4; ++j) {
      acc1[i][j] = (f32x4){0.f, 0.f, 0.f, 0.f};
      acc3[i][j] = (f32x4){0.f, 0.f, 0.f, 0.f};
    }

#define UP_STAGE(B, K0)                                                              \
  do {                                                                               \
    _Pragma("unroll")                                                                \
    for (int j = 0; j < 2; ++j)                                                      \
      gl2lds16(hbf + aoff[j] + (K0), &As[B][(size_t)(tid + 256 * j) * 8]);           \
    _Pragma("unroll")                                                                \
    for (int j = 0; j < 2; ++j)                                                      \
      gl2lds16(B1p + boff[j] + (K0), &Bs1[B][(size_t)(tid + 256 * j) * 8]);          \
    _Pragma("unroll")                                                                \
    for (int j = 0; j < 2; ++j)                                                      \
      gl2lds16(B3p + boff[j] + (K0), &Bs3[B][(size_t)(tid + 256 * j) * 8]);          \
  } while (0)

#define UP_COMPUTE(B)                                                                \
  do {                                                                               \
    const u16* Ab = &As[B][0];                                                       \
    const u16* B1b = &Bs1[B][0];                                                     \
    const u16* B3b = &Bs3[B][0];                                                     \
    bf16x8 af[4];                                                                    \
    _Pragma("unroll")                                                                \
    for (int i = 0; i < 4; ++i) af[i] = FRAG32(Ab, wr + i * 16 + lr);                \
    _Pragma("unroll")                                                                \
    for (int j = 0; j < 4; ++j) {                                                    \
      bf16x8 b1 = FRAG32(B1b, wc + j * 16 + lr);                                     \
      _Pragma("unroll")                                                              \
      for (int i = 0; i < 4; ++i)                                                    \
        acc1[i][j] = __builtin_amdgcn_mfma_f32_16x16x32_bf16(af[i], b1, acc1[i][j], 0, 0, 0); \
      bf16x8 b3 = FRAG32(B3b, wc + j * 16 + lr);                                     \
      _Pragma("unroll")                                                              \
      for (int i = 0; i < 4; ++i)                                                    \
        acc3[i][j] = __builtin_amdgcn_mfma_f32_16x16x32_bf16(af[i], b3, acc3[i][j], 0, 0, 0); \
    }                                                                                \
  } while (0)

  // 2-phase pipeline: stage(next) issued BEFORE compute(cur); one barrier per K-step.
  UP_STAGE(0, 0);
  __syncthreads();
  int cur = 0;
  const int NT = DM / 32;
#pragma unroll 1
  for (int t = 0; t < NT - 1; ++t) {
    UP_STAGE(cur ^ 1, (t + 1) * 32);
    UP_COMPUTE(cur);
    __syncthreads();
    cur ^= 1;
  }
  UP_COMPUTE(cur);

#pragma unroll
  for (int i = 0; i < 4; ++i)
#pragma unroll
    for (int r = 0; r < 4; ++r) {
      int row = m0 + wr + i * 16 + lq * 4 + r;
      u16* crow = Cp + (size_t)row * N;
#pragma unroll
      for (int j = 0; j < 4; ++j) {
        float v1 = acc1[i][j][r];
        float v3 = acc3[i][j][r];
        float h = (v1 / (1.f + __expf(-v1))) * v3;   // silu(v1)*v3
        crow[n0 + wc + j * 16 + lr] = f2bf(h);
      }
    }
}

// ============ DOWN: 128x128 tile, 4 waves (64x64 each), BK=32, single-B, dbuf ========
// swz < 256: shared (A=hs, B=ws2t, K=DFS) -> out fp32 (covers every element)
// swz >= 256: routed (A=hexp[e], B=w2t[e], K=DFF) -> ob bf16 per-slot rows
__global__ __launch_bounds__(256, 4) void k_down(
    const u16* __restrict__ hs, const u16* __restrict__ ws2t,
    const u16* __restrict__ hexp, const u16* __restrict__ w2t,
    float* __restrict__ out, u16* __restrict__ ob,
    const int* __restrict__ counts) {
  const int tid = threadIdx.x;
  const int nwg = 256 + NE * 64;   // 1280, divisible by 8
  int bid = (int)blockIdx.x;
  bid = (bid & 7) * (nwg >> 3) + (bid >> 3);

  const u16* Ap; const u16* Bp;
  int m0, n0, K, e = -1;
  if (bid < 256) {
    m0 = (bid >> 3) * 128; n0 = (bid & 7) * 128;
    Ap = hs; Bp = ws2t; K = DFS;
  } else {
    int r = bid - 256;                  // 1024 routed: e * (8 m-tiles x 8 n-tiles)
    e = r >> 6; int q = r & 63;
    m0 = (q >> 3) * 128; n0 = (q & 7) * 128;
    int cnt = counts[e]; if (cnt > CAP) cnt = CAP;
    if (m0 >= cnt) return;
    Ap = hexp + (size_t)e * (CAP * DFF);
    Bp = w2t + (size_t)e * (DM * DFF);
    K = DFF;
  }

  __shared__ __align__(16) u16 As[2][128 * 32];   // 16 KB
  __shared__ __align__(16) u16 Bs[2][128 * 32];   // 16 KB -> 32 KB total

  uint32_t aoff[2], boff[2];
#pragma unroll
  for (int j = 0; j < 2; ++j) {
    int L = tid + 256 * j;
    int row = L >> 2;
    int c = (L & 3) ^ ((row >> 1) & 3);
    aoff[j] = (uint32_t)(m0 + row) * K + c * 8;
    boff[j] = (uint32_t)(n0 + row) * K + c * 8;
  }

  const int lane = tid & 63;
  const int wv = tid >> 6;
  const int wr = (wv >> 1) * 64;
  const int wc = (wv & 1) * 64;
  const int lr = lane & 15;
  const int lq = lane >> 4;

  f32x4 acc[4][4];
#pragma unroll
  for (int i = 0; i < 4; ++i)
#pragma unroll
    for (int j = 0; j < 4; ++j) acc[i][j] = (f32x4){0.f, 0.f, 0.f, 0.f};

#define DN_STAGE(B, K0)                                                              \
  do {                                                                               \
    _Pragma("unroll")                                                                \
    for (int j = 0; j < 2; ++j)                                                      \
      gl2lds16(Ap + aoff[j] + (K0), &As[B][(size_t)(tid + 256 * j) * 8]);            \
    _Pragma("unroll")                                                                \
    for (int j = 0; j < 2; ++j)                                                      \
      gl2lds16(Bp + boff[j] + (K0), &Bs[B][(size_t)(tid + 256 * j) * 8]);            \
  } while (0)

#define DN_COMPUTE(B)                                                                \
  do {                                                                               \
    const u16* Ab = &As[B][0];                                                       \
    const u16* Bb = &Bs[B][0];                                                       \
    bf16x8 af[4];                                                                    \
    _Pragma("unroll")                                                                \
    for (int i = 0; i < 4; ++i) af[i] = FRAG32(Ab, wr + i * 16 + lr);                \
    _Pragma("unroll")                                                                \
    for (int j = 0; j < 4; ++j) {                                                    \
      bf16x8 br = FRAG32(Bb, wc + j * 16 + lr);                                      \
      _Pragma("unroll")                                                              \
      for (int i = 0; i < 4; ++i)                                                    \
        acc[i][j] = __builtin_amdgcn_mfma_f32_16x16x32_bf16(af[i], br, acc[i][j], 0, 0, 0); \
    }                                                                                \
  } while (0)

  DN_STAGE(0, 0);
  __syncthreads();
  int cur = 0;
  const int NT = K / 32;
#pragma unroll 1
  for (int t = 0; t < NT - 1; ++t) {
    DN_STAGE(cur ^ 1, (t + 1) * 32);
    DN_COMPUTE(cur);
    __syncthreads();
    cur ^= 1;
  }
  DN_COMPUTE(cur);

  if (e < 0) {
#pragma unroll
    for (int i = 0; i < 4; ++i)
#pragma unroll
      for (int r = 0; r < 4; ++r) {
        int row = m0 + wr + i * 16 + lq * 4 + r;
        float* orow = out + (size_t)row * DM;
#pragma unroll
        for (int j = 0; j < 4; ++j)
          orow[n0 + wc + j * 16 + lr] = acc[i][j][r];
      }
  } else {
    u16* obase = ob + (size_t)e * CAP * DM;
#pragma unroll
    for (int i = 0; i < 4; ++i)
#pragma unroll
      for (int r = 0; r < 4; ++r) {
        int row = m0 + wr + i * 16 + lq * 4 + r;
        u16* orow = obase + (size_t)row * DM;
#pragma unroll
        for (int j = 0; j < 4; ++j)
          orow[n0 + wc + j * 16 + lr] = f2bf(acc[i][j][r]);
      }
  }
}

// ============ COMBINE: out[t] += w0*ob[s0] + w1*ob[s1] ============
__global__ __launch_bounds__(256) void k_combine(
    float* __restrict__ out, const u16* __restrict__ ob,
    const int* __restrict__ tslot, const float* __restrict__ tw) {
  int t = blockIdx.x;
  int c = threadIdx.x * 4;
  int s0 = tslot[2 * t], s1 = tslot[2 * t + 1];
  float w0 = tw[2 * t], w1 = tw[2 * t + 1];
  float4 v = *(float4*)&out[(size_t)t * DM + c];
  if (s0 >= 0) {
    ushort4 o = *(const ushort4*)&ob[(size_t)s0 * DM + c];
    v.x += w0 * bf2f(o.x); v.y += w0 * bf2f(o.y);
    v.z += w0 * bf2f(o.z); v.w += w0 * bf2f(o.w);
  }
  if (s1 >= 0) {
    ushort4 o = *(const ushort4*)&ob[(size_t)s1 * DM + c];
    v.x += w1 * bf2f(o.x); v.y += w1 * bf2f(o.y);
    v.z += w1 * bf2f(o.z); v.w += w1 * bf2f(o.w);
  }
  *(float4*)&out[(size_t)t * DM + c] = v;
}

// ---------------- host ----------------
extern "C" void kernel_launch(void* const* d_in, const int* in_sizes, int n_in,
                              void* d_out, int out_size, void* d_ws, size_t ws_size,
                              hipStream_t stream) {
  (void)in_sizes; (void)n_in; (void)out_size; (void)ws_size;
  const float* x   = (const float*)d_in[0];
  const float* Wg  = (const float*)d_in[1];
  const float* w1  = (const float*)d_in[2];
  const float* w3  = (const float*)d_in[3];
  const float* w2  = (const float*)d_in[4];
  const float* ws1 = (const float*)d_in[5];
  const float* ws3 = (const float*)d_in[6];
  const float* ws2 = (const float*)d_in[7];
  float* out = (float*)d_out;
  char* ws = (char*)d_ws;

  u16* hbf   = (u16*)(ws + 0);          // 8 MB   [TT,DM] bf16          (dead after k_up)
  u16* w1t   = (u16*)(ws + 8388608);    // 16 MB  [E][DFF][DM]          (dead after k_up)
  u16* w3t   = (u16*)(ws + 25165824);   // 16 MB                        (dead after k_up)
  u16* w2t   = (u16*)(ws + 41943040);   // 16 MB  [E][DM][DFF]
  u16* ws1t  = (u16*)(ws + 58720256);   // 2 MB   [DFS][DM]
  u16* ws3t  = (u16*)(ws + 60817408);   // 2 MB
  u16* ws2t  = (u16*)(ws + 62914560);   // 2 MB   [DM][DFS]
  u16* hs    = (u16*)(ws + 65011712);   // 8 MB   [TT,DFS] bf16
  u16* hexp  = (u16*)(ws + 73400320);   // 16 MB  [E][CAP][DFF] bf16
  int* counts    = (int*)(ws + 90177536);
  int* tok_slot  = (int*)(ws + 90177792);   // 64 KB
  int* tslot     = (int*)(ws + 90243328);   // 32 KB [TT*2]
  float* tw      = (float*)(ws + 90276096); // 32 KB [TT*2]
  u16* ob    = (u16*)(ws + 0);          // 33.5 MB [E*CAP, DM] bf16 — aliases hbf/w1t/w3t
                                        // (written only in k_down, after those are dead)

  hipMemsetAsync(counts, 0, NE * sizeof(int), stream);

  // prep: 256 router blocks + 51*256 transpose blocks
  k_prep<<<dim3(256 + 51 * 256), dim3(256), 0, stream>>>(
      x, Wg, w1, w3, w2, ws1, ws3, ws2,
      hbf, w1t, w3t, w2t, ws1t, ws3t, ws2t,
      counts, tok_slot, tslot, tw);

  // up: 256 shared tiles (32m x 8n) + 512 routed tiles (16e x 8m x 4n)
  k_up<<<dim3(256 + NE * 32), dim3(256), 0, stream>>>(
      hbf, ws1t, ws3t, w1t, w3t, hs, hexp, counts, tok_slot);

  // down: 256 shared tiles -> out (plain fp32) + 1024 routed tiles -> ob bf16
  k_down<<<dim3(256 + NE * 64), dim3(256), 0, stream>>>(
      hs, ws2t, hexp, w2t, out, ob, counts);

  // combine: out[t] += w0*ob[s0] + w1*ob[s1]
  k_combine<<<dim3(TT), dim3(256), 0, stream>>>(out, ob, tslot, tw);
}